// Round 1
// baseline (1257.106 us; speedup 1.0000x reference)
//
#include <hip/hip_runtime.h>

typedef unsigned short u16;
typedef unsigned int u32;
typedef __attribute__((ext_vector_type(8))) short bf16x8;
typedef __attribute__((ext_vector_type(4))) float f32x4;
typedef __attribute__((ext_vector_type(8))) unsigned short u16x8;
typedef const __attribute__((address_space(1))) void gvoid;
typedef __attribute__((address_space(3))) void svoid;

#define T_TOK 100352
#define CDIM 256

__device__ __forceinline__ u16 f2bf(float f) {
    u32 u = __float_as_uint(f);
    u32 r = (u + 0x7fffu + ((u >> 16) & 1u)) >> 16;
    return (u16)r;
}
__device__ __forceinline__ float bf2f(u16 h) {
    return __uint_as_float(((u32)h) << 16);
}
__device__ __forceinline__ float gelu_f(float x) {
    return 0.5f * x * (1.0f + erff(x * 0.70710678118654752f));
}

// ---------------- fp32 -> bf16 weight conversion ----------------
__global__ void cvt_kernel(const float* __restrict__ in, u16* __restrict__ out, int n) {
    int i = blockIdx.x * 256 + threadIdx.x;
    if (i < n) out[i] = f2bf(in[i]);
}

// ---------------- LayerNorm (fp32 in, bf16 out) ----------------
// one wave per token, lane l handles channels 4l..4l+3
__global__ __launch_bounds__(256) void ln_kernel(
    const float* __restrict__ X, const float* __restrict__ w,
    const float* __restrict__ b, u16* __restrict__ Y)
{
    int wid = threadIdx.x >> 6, l = threadIdx.x & 63;
    int t = blockIdx.x * 4 + wid;
    const float4 x4 = ((const float4*)(X + (size_t)t * CDIM))[l];
    float s  = x4.x + x4.y + x4.z + x4.w;
    float s2 = x4.x*x4.x + x4.y*x4.y + x4.z*x4.z + x4.w*x4.w;
    #pragma unroll
    for (int o = 32; o; o >>= 1) { s += __shfl_xor(s, o); s2 += __shfl_xor(s2, o); }
    float mean = s * (1.0f/256.0f);
    float var  = s2 * (1.0f/256.0f) - mean*mean;
    float rstd = rsqrtf(var + 1e-5f);
    float4 w4 = ((const float4*)w)[l];
    float4 b4 = ((const float4*)b)[l];
    ushort4 o4;
    o4.x = f2bf((x4.x - mean)*rstd*w4.x + b4.x);
    o4.y = f2bf((x4.y - mean)*rstd*w4.y + b4.y);
    o4.z = f2bf((x4.z - mean)*rstd*w4.z + b4.z);
    o4.w = f2bf((x4.w - mean)*rstd*w4.w + b4.w);
    ((ushort4*)(Y + (size_t)t * CDIM))[l] = o4;
}

// ---------------- bf16 MFMA GEMM:  out[M,N] = A[M,K] @ B[N,K]^T + bias ----------------
// 128x128 tile, BK=32, 256 threads (4 waves, 2x2), wave computes 64x64.
// EPI: 0 = bf16 store, 1 = gelu -> bf16 store, 2 = fp32 + residual store
template<int EPI>
__global__ __launch_bounds__(256) void gemm_kernel(
    const u16* __restrict__ A, const u16* __restrict__ Bw,
    const float* __restrict__ bias, void* __restrict__ outp,
    const float* __restrict__ res, int N, int K)
{
    __shared__ u16 lsA[128 * 32];
    __shared__ u16 lsB[128 * 32];
    const int l = threadIdx.x & 63;
    const int w = threadIdx.x >> 6;
    const int mT = blockIdx.y, nT = blockIdx.x;
    const int wr = w >> 1, wc = w & 1;

    f32x4 acc[4][4];
    #pragma unroll
    for (int m = 0; m < 4; ++m)
        #pragma unroll
        for (int n = 0; n < 4; ++n) acc[m][n] = (f32x4){0.f,0.f,0.f,0.f};

    const int rsub = l >> 2;          // 0..15
    const int ksub = (l & 3) * 8;     // 0,8,16,24 bf16 elems (16B chunks)

    for (int kt = 0; kt < K; kt += 32) {
        __syncthreads();
        #pragma unroll
        for (int i = 0; i < 2; ++i) {
            int row = i*64 + w*16 + rsub;
            const u16* ga = A  + (size_t)(mT*128 + row) * K + kt + ksub;
            const u16* gb = Bw + (size_t)(nT*128 + row) * K + kt + ksub;
            u16* la = lsA + i*2048 + w*512;
            u16* lb = lsB + i*2048 + w*512;
            __builtin_amdgcn_global_load_lds((gvoid*)ga, (svoid*)la, 16, 0, 0);
            __builtin_amdgcn_global_load_lds((gvoid*)gb, (svoid*)lb, 16, 0, 0);
        }
        __syncthreads();
        const int lr = l & 15;
        const int lk = (l >> 4) * 8;
        bf16x8 a[4], b[4];
        #pragma unroll
        for (int m = 0; m < 4; ++m) a[m] = *(const bf16x8*)&lsA[(wr*64 + m*16 + lr)*32 + lk];
        #pragma unroll
        for (int n = 0; n < 4; ++n) b[n] = *(const bf16x8*)&lsB[(wc*64 + n*16 + lr)*32 + lk];
        #pragma unroll
        for (int m = 0; m < 4; ++m)
            #pragma unroll
            for (int n = 0; n < 4; ++n)
                acc[m][n] = __builtin_amdgcn_mfma_f32_16x16x32_bf16(a[m], b[n], acc[m][n], 0, 0, 0);
    }

    const int lr4 = (l >> 4) * 4;
    const int lcn = l & 15;
    #pragma unroll
    for (int m = 0; m < 4; ++m) {
        #pragma unroll
        for (int n = 0; n < 4; ++n) {
            int row0 = mT*128 + wr*64 + m*16 + lr4;
            int col  = nT*128 + wc*64 + n*16 + lcn;
            float bb = bias[col];
            #pragma unroll
            for (int j = 0; j < 4; ++j) {
                size_t idx = (size_t)(row0 + j) * N + col;
                float v = acc[m][n][j] + bb;
                if (EPI == 0)      ((u16*)outp)[idx] = f2bf(v);
                else if (EPI == 1) ((u16*)outp)[idx] = f2bf(gelu_f(v));
                else               ((float*)outp)[idx] = v + res[idx];
            }
        }
    }
}

// ---------------- windowed attention, one wave per (window, head) ----------------
// qkv: bf16 [T][768] (q|k|v each 256 = 8 heads * 32), out: bf16 [T][256]
__global__ __launch_bounds__(64) void attn_kernel(
    const u16* __restrict__ qkv, const float* __restrict__ rpb,
    u16* __restrict__ outb, int shift)
{
    __shared__ float k_lds[49][32];
    __shared__ float v_lds[49][32];
    __shared__ float bias_lds[169];
    __shared__ int   tok_lds[49];

    const int l = threadIdx.x;
    const int h   = blockIdx.x & 7;
    const int win = blockIdx.x >> 3;
    const int wj = win & 15, wi = (win >> 4) & 15, bb = win >> 8;

    if (l < 49) {
        int i = l / 7, j = l - i*7;
        int rr = wi*7 + i + shift; if (rr >= 112) rr -= 112;
        int cc = wj*7 + j + shift; if (cc >= 112) cc -= 112;
        tok_lds[l] = bb*12544 + rr*112 + cc;
    }
    for (int r = l; r < 169; r += 64) bias_lds[r] = rpb[r*8 + h];
    __syncthreads();

    // stage K, V into LDS (fp32)
    {
        const int rs = l >> 2, lc = l & 3;
        #pragma unroll
        for (int r0 = 0; r0 < 64; r0 += 16) {
            int r = r0 + rs;
            if (r < 49) {
                const u16x8* src = (const u16x8*)(qkv + (size_t)tok_lds[r]*768 + h*32);
                u16x8 kv = src[32 + lc];
                u16x8 vv = src[64 + lc];
                #pragma unroll
                for (int e = 0; e < 8; ++e) {
                    k_lds[r][lc*8 + e] = bf2f(kv[e]);
                    v_lds[r][lc*8 + e] = bf2f(vv[e]);
                }
            }
        }
    }
    __syncthreads();

    const int qi = (l < 49) ? l : 48;
    const int iq = qi / 7, jq = qi - iq*7;

    // q row into registers (scaled)
    float q[32];
    {
        const u16x8* src = (const u16x8*)(qkv + (size_t)tok_lds[qi]*768 + h*32);
        #pragma unroll
        for (int c = 0; c < 4; ++c) {
            u16x8 qv = src[c];
            #pragma unroll
            for (int e = 0; e < 8; ++e) q[c*8+e] = bf2f(qv[e]) * 0.17677669529663687f;
        }
    }

    int regq = 0;
    if (shift > 0) {
        int rr = wi*7 + iq, cc = wj*7 + jq;   // rolled coords
        int hr = rr < 105 ? 0 : (rr < 109 ? 1 : 2);
        int wr = cc < 105 ? 0 : (cc < 109 ? 1 : 2);
        regq = hr*3 + wr;
    }

    // S = q @ K^T + bias (+mask)
    float S[49];
    #pragma unroll
    for (int kj = 0; kj < 49; ++kj) {
        const float4* kr = (const float4*)k_lds[kj];
        float s0=0.f, s1=0.f, s2=0.f, s3=0.f;
        #pragma unroll
        for (int c = 0; c < 8; ++c) {
            float4 kv = kr[c];
            s0 += q[c*4+0]*kv.x; s1 += q[c*4+1]*kv.y;
            s2 += q[c*4+2]*kv.z; s3 += q[c*4+3]*kv.w;
        }
        int ik = kj / 7, jk = kj - ik*7;
        int rel = (iq - ik + 6)*13 + (jq - jk + 6);
        float s = (s0+s1)+(s2+s3) + bias_lds[rel];
        if (shift > 0) {
            int rr = wi*7 + ik, cc = wj*7 + jk;
            int hr = rr < 105 ? 0 : (rr < 109 ? 1 : 2);
            int wr = cc < 105 ? 0 : (cc < 109 ? 1 : 2);
            if (hr*3 + wr != regq) s -= 100.0f;
        }
        S[kj] = s;
    }

    // softmax over 49 (in registers)
    float mx = -1e30f;
    #pragma unroll
    for (int kj = 0; kj < 49; ++kj) mx = fmaxf(mx, S[kj]);
    float sum = 0.f;
    #pragma unroll
    for (int kj = 0; kj < 49; ++kj) { S[kj] = __expf(S[kj] - mx); sum += S[kj]; }
    float inv = 1.0f / sum;

    // O = S @ V
    float o[32];
    #pragma unroll
    for (int d = 0; d < 32; ++d) o[d] = 0.f;
    #pragma unroll
    for (int kj = 0; kj < 49; ++kj) {
        float p = S[kj];
        const float4* vr = (const float4*)v_lds[kj];
        #pragma unroll
        for (int c = 0; c < 8; ++c) {
            float4 vv = vr[c];
            o[c*4+0] += p*vv.x; o[c*4+1] += p*vv.y;
            o[c*4+2] += p*vv.z; o[c*4+3] += p*vv.w;
        }
    }

    if (l < 49) {
        u16x8* dst = (u16x8*)(outb + (size_t)tok_lds[qi]*256 + h*32);
        #pragma unroll
        for (int c = 0; c < 4; ++c) {
            u16x8 pk;
            #pragma unroll
            for (int e = 0; e < 8; ++e) pk[e] = f2bf(o[c*8+e] * inv);
            dst[c] = pk;
        }
    }
}

// ---------------- host ----------------
extern "C" void kernel_launch(void* const* d_in, const int* in_sizes, int n_in,
                              void* d_out, int out_size, void* d_ws, size_t ws_size,
                              hipStream_t stream) {
    const float* x_in   = (const float*)d_in[0];
    const float* ln1_w  = (const float*)d_in[1];
    const float* ln1_b  = (const float*)d_in[2];
    const float* qkv_w  = (const float*)d_in[3];
    const float* qkv_b  = (const float*)d_in[4];
    const float* proj_w = (const float*)d_in[5];
    const float* proj_b = (const float*)d_in[6];
    const float* rpb    = (const float*)d_in[7];
    const float* ln2_w  = (const float*)d_in[8];
    const float* ln2_b  = (const float*)d_in[9];
    const float* mlp_w1 = (const float*)d_in[10];
    const float* mlp_b1 = (const float*)d_in[11];
    const float* mlp_w2 = (const float*)d_in[12];
    const float* mlp_b2 = (const float*)d_in[13];
    float* xout = (float*)d_out;

    char* p = (char*)d_ws;
    u16* wq = (u16*)p;  p += (size_t)2*768*256*2;
    u16* wp = (u16*)p;  p += (size_t)2*256*256*2;
    u16* w1 = (u16*)p;  p += (size_t)2*1024*256*2;
    u16* w2 = (u16*)p;  p += (size_t)2*256*1024*2;
    u16* buf_y   = (u16*)p; p += (size_t)T_TOK*256*2;
    u16* buf_big = (u16*)p;   // T*1024 bf16 max (holds qkv [T*768] and mlp hidden [T*1024])

    // convert weights to bf16 (both layers at once; tensors are contiguous [D,...])
    {
        int n;
        n = 2*768*256;  cvt_kernel<<<(n+255)/256, 256, 0, stream>>>(qkv_w,  wq, n);
        n = 2*256*256;  cvt_kernel<<<(n+255)/256, 256, 0, stream>>>(proj_w, wp, n);
        n = 2*1024*256; cvt_kernel<<<(n+255)/256, 256, 0, stream>>>(mlp_w1, w1, n);
        n = 2*256*1024; cvt_kernel<<<(n+255)/256, 256, 0, stream>>>(mlp_w2, w2, n);
    }

    for (int i = 0; i < 2; ++i) {
        const int shift = (i == 0) ? 0 : 3;
        const float* xcur = (i == 0) ? x_in : xout;

        // LN1 -> y (bf16)
        ln_kernel<<<T_TOK/4, 256, 0, stream>>>(xcur, ln1_w + i*256, ln1_b + i*256, buf_y);
        // QKV: y @ qkv_w^T + b -> buf_big bf16 [T][768]
        gemm_kernel<0><<<dim3(6, T_TOK/128), 256, 0, stream>>>(
            buf_y, wq + (size_t)i*768*256, qkv_b + i*768, buf_big, nullptr, 768, 256);
        // windowed attention -> buf_y bf16 [T][256]
        attn_kernel<<<16384, 64, 0, stream>>>(buf_big, rpb + i*169*8, buf_y, shift);
        // proj + residual -> xout fp32
        gemm_kernel<2><<<dim3(2, T_TOK/128), 256, 0, stream>>>(
            buf_y, wp + (size_t)i*256*256, proj_b + i*256, xout, xcur, 256, 256);
        // LN2 -> y (bf16)
        ln_kernel<<<T_TOK/4, 256, 0, stream>>>(xout, ln2_w + i*256, ln2_b + i*256, buf_y);
        // MLP1 + gelu -> buf_big bf16 [T][1024]
        gemm_kernel<1><<<dim3(8, T_TOK/128), 256, 0, stream>>>(
            buf_y, w1 + (size_t)i*1024*256, mlp_b1 + i*1024, buf_big, nullptr, 1024, 256);
        // MLP2 + residual -> xout fp32
        gemm_kernel<2><<<dim3(2, T_TOK/128), 256, 0, stream>>>(
            buf_big, w2 + (size_t)i*256*1024, mlp_b2 + i*256, xout, xout, 256, 1024);
    }
}